// Round 2
// baseline (357.554 us; speedup 1.0000x reference)
//
#include <hip/hip_runtime.h>
#include <hip/hip_bf16.h>

// Problem constants (B,C,H,W fixed by the reference)
#define B_    4
#define C_    64
#define H_    192
#define W_    192
#define TAPS_ 9
#define MID_  12
#define HW_   (H_ * W_)

constexpr float STD_ = 0.47140452079103173f;  // sqrt(2)/3

using bf16 = __hip_bfloat16;

__device__ __forceinline__ float b2f(bf16 v) { return __bfloat162float(v); }
__device__ __forceinline__ float lo16(unsigned u) { return __uint_as_float(u << 16); }
__device__ __forceinline__ float hi16(unsigned u) { return __uint_as_float(u & 0xffff0000u); }

// dtype-agnostic scalar load: fl=1 -> float32, fl=0 -> bf16
__device__ __forceinline__ float ldg1(const void* p, int fl, size_t i) {
    return fl ? ((const float*)p)[i]
              : __bfloat162float(((const bf16*)p)[i]);
}

union U8 { uint4 u; bf16 h[8]; };

// ---------------------------------------------------------------------------
// Kernel 0: dtype detector. Read leading 16-bit slots of x and sw AS bf16
// (always in-bounds under either dtype). If underlying data is f32, the
// low-half slots are uniform random bits -> magnitudes up to ~1e38 with
// probability ~1. If bf16, |x|<~6, |sw|<~0.3. flag=1 means float32.
// ---------------------------------------------------------------------------
__global__ __launch_bounds__(256) void k_detect(const void* __restrict__ x,
                                                const void* __restrict__ sw,
                                                int* __restrict__ flag) {
    int tid = threadIdx.x;
    const unsigned short* px = (const unsigned short*)x;
    const unsigned short* ps = (const unsigned short*)sw;
    float m = 0.f;
    for (int i = tid; i < 4096; i += 256) {
        float v = __uint_as_float(((unsigned)px[i]) << 16);
        float a = fabsf(v);
        if (v != v || a > 1e30f) a = 1e31f;
        m = fmaxf(m, a);
    }
    for (int i = tid; i < 512; i += 256) {
        float v = __uint_as_float(((unsigned)ps[i]) << 16);
        float a = fabsf(v);
        if (v != v || a > 1e30f) a = 1e31f;
        m = fmaxf(m, a);
    }
    #pragma unroll
    for (int off = 32; off; off >>= 1) m = fmaxf(m, __shfl_down(m, off));
    __shared__ float red[4];
    if ((tid & 63) == 0) red[tid >> 6] = m;
    __syncthreads();
    if (tid == 0) {
        float mm = fmaxf(fmaxf(red[0], red[1]), fmaxf(red[2], red[3]));
        *flag = (mm > 100.f) ? 1 : 0;
    }
}

// ---------------------------------------------------------------------------
// Kernel 1: g[b,c] = mean over H*W of x[b,c,:,:]   (one block per (b,c))
// ---------------------------------------------------------------------------
__global__ __launch_bounds__(256) void k_mean(const void* __restrict__ x,
                                              const int* __restrict__ flag,
                                              float* __restrict__ g) {
    int fl = *flag;
    int bc = blockIdx.x;  // 0..255
    float s = 0.f;
    if (fl) {
        const float4* p = (const float4*)((const float*)x + (size_t)bc * HW_);
        for (int i = threadIdx.x; i < HW_ / 4; i += 256) {
            float4 u = p[i];
            s += u.x + u.y + u.z + u.w;
        }
    } else {
        const uint2* p = (const uint2*)((const bf16*)x + (size_t)bc * HW_);
        for (int i = threadIdx.x; i < HW_ / 4; i += 256) {
            uint2 u = p[i];
            s += lo16(u.x) + hi16(u.x) + lo16(u.y) + hi16(u.y);
        }
    }
    #pragma unroll
    for (int off = 32; off; off >>= 1) s += __shfl_down(s, off);
    __shared__ float red[4];
    if ((threadIdx.x & 63) == 0) red[threadIdx.x >> 6] = s;
    __syncthreads();
    if (threadIdx.x == 0)
        g[bc] = (red[0] + red[1] + red[2] + red[3]) * (1.0f / HW_);
}

// ---------------------------------------------------------------------------
// Kernel 2: channel-filter branch.
//   h1 = relu(g @ cw1^T + cb1)            (B, 12)
//   cf = (h1 @ cw2^T + cb2) -> (B,C,9)    FilterNorm over the 9 taps
// One block, 256 threads (= B*C).
// ---------------------------------------------------------------------------
__global__ __launch_bounds__(256) void k_cf(const float* __restrict__ g,
                                            const void* __restrict__ cw1,
                                            const void* __restrict__ cb1,
                                            const void* __restrict__ cw2,
                                            const void* __restrict__ cb2,
                                            const int* __restrict__ flag,
                                            float* __restrict__ cfn) {
    int fl = *flag;
    __shared__ float g_l[B_ * C_];
    __shared__ float h1_l[B_ * MID_];
    int tid = threadIdx.x;
    g_l[tid] = g[tid];
    __syncthreads();
    if (tid < B_ * MID_) {
        int b = tid / MID_, m = tid % MID_;
        float acc = ldg1(cb1, fl, m);
        for (int c = 0; c < C_; ++c) acc += g_l[b * C_ + c] * ldg1(cw1, fl, m * C_ + c);
        h1_l[tid] = fmaxf(acc, 0.f);
    }
    __syncthreads();
    int b = tid >> 6, c = tid & 63;
    float f[TAPS_];
    float mean = 0.f;
    #pragma unroll
    for (int t = 0; t < TAPS_; ++t) {
        int n = c * TAPS_ + t;
        float acc = ldg1(cb2, fl, n);
        #pragma unroll
        for (int m = 0; m < MID_; ++m) acc += h1_l[b * MID_ + m] * ldg1(cw2, fl, n * MID_ + m);
        f[t] = acc;
        mean += acc;
    }
    mean *= (1.f / TAPS_);
    float var = 0.f;
    #pragma unroll
    for (int t = 0; t < TAPS_; ++t) { float d = f[t] - mean; var += d * d; }
    var *= (1.f / (TAPS_ - 1));  // ddof=1
    float scale = STD_ / (sqrtf(fmaxf(var, 0.f)) + 1e-10f);
    #pragma unroll
    for (int t = 0; t < TAPS_; ++t)
        cfn[(b * C_ + c) * TAPS_ + t] = (f[t] - mean) * scale;
}

// ---------------------------------------------------------------------------
// Kernel 3 (fused main): one block per (b, h) row.
//   Phase A: s[9][192] = FilterNorm_t( x[b,:,h,:] . sw^T + sb )
//   Phase B: a[64][192] = leaky( sum_t xpad[c, h-1+i, w-1+j]*s[t][w]*cf[c][t] )
//   Phase C: out[b,o,h,:] = x + b2[o] + sum_{c,k} a[c][w-4+k]*w2[o,c,k]
// The 1x9 conv only couples along W, so the entire chain is row-local.
// ---------------------------------------------------------------------------
__global__ __launch_bounds__(256) void k_main(const void* __restrict__ x,
                                              const void* __restrict__ sw,
                                              const void* __restrict__ sb,
                                              const float* __restrict__ cfn,
                                              const void* __restrict__ w2,
                                              const void* __restrict__ bias2,
                                              const int* __restrict__ flag,
                                              void* __restrict__ out) {
    int fl = *flag;
    int bh = blockIdx.x;
    int bb = bh / H_;
    int h  = bh % H_;
    int tid = threadIdx.x;

    __shared__ float sw_l[TAPS_ * C_];   // 2304 B
    __shared__ float cf_l[C_ * TAPS_];   // 2304 B
    __shared__ float sb_l[TAPS_];
    __shared__ float s_l[TAPS_ * W_];    // 6912 B
    __shared__ float a_l[C_ * W_];       // 49152 B

    for (int i = tid; i < TAPS_ * C_; i += 256) sw_l[i] = ldg1(sw, fl, i);
    for (int i = tid; i < C_ * TAPS_; i += 256) cf_l[i] = cfn[bb * C_ * TAPS_ + i];
    if (tid < TAPS_) sb_l[tid] = ldg1(sb, fl, tid);
    __syncthreads();

    // ---- Phase A: spatial filters for this row ----
    if (tid < W_) {
        int w = tid;
        float acc[TAPS_];
        #pragma unroll
        for (int t = 0; t < TAPS_; ++t) acc[t] = sb_l[t];
        size_t base = (size_t)bb * C_ * HW_ + (size_t)h * W_ + w;
        #pragma unroll 4
        for (int c = 0; c < C_; ++c) {
            float xv = ldg1(x, fl, base + (size_t)c * HW_);
            #pragma unroll
            for (int t = 0; t < TAPS_; ++t) acc[t] += xv * sw_l[t * C_ + c];
        }
        float mean = 0.f;
        #pragma unroll
        for (int t = 0; t < TAPS_; ++t) mean += acc[t];
        mean *= (1.f / TAPS_);
        float var = 0.f;
        #pragma unroll
        for (int t = 0; t < TAPS_; ++t) { float d = acc[t] - mean; var += d * d; }
        var *= (1.f / (TAPS_ - 1));
        float scale = STD_ / (sqrtf(fmaxf(var, 0.f)) + 1e-10f);
        #pragma unroll
        for (int t = 0; t < TAPS_; ++t) s_l[t * W_ + w] = (acc[t] - mean) * scale;
    }
    __syncthreads();

    // ---- Phase B: DDF apply + leaky relu, row (64 channels x 192 pixels) ----
    size_t bbase = (size_t)bb * C_ * HW_;
    #pragma unroll 1
    for (int k = 0; k < 48; ++k) {  // 48*256 = 12288 = 64*192
        int p = tid + k * 256;
        int c = p / W_;
        int w = p - c * W_;
        float acc = 0.f;
        #pragma unroll
        for (int t = 0; t < TAPS_; ++t) {
            int i = t / 3, j = t % 3;
            int hh = h - 1 + i, ww = w - 1 + j;
            float xv = 0.f;
            if (hh >= 0 && hh < H_ && ww >= 0 && ww < W_)
                xv = ldg1(x, fl, bbase + (size_t)c * HW_ + (size_t)hh * W_ + ww);
            acc += xv * s_l[t * W_ + w] * cf_l[c * TAPS_ + t];
        }
        a_l[c * W_ + w] = (acc >= 0.f) ? acc : 0.1f * acc;
    }
    __syncthreads();

    // ---- Phase C: 1x9 conv along W + bias + residual ----
    int o   = tid >> 2;         // 64 output channels
    int sub = tid & 3;          // 4 threads per o, 48 pixels each
    int w0  = sub * 48;

    float acc[48];
    #pragma unroll
    for (int i = 0; i < 48; ++i) acc[i] = 0.f;

    #pragma unroll 1
    for (int c = 0; c < C_; ++c) {
        float av[56];
        #pragma unroll
        for (int i = 0; i < 56; ++i) {
            int idx = w0 - 4 + i;
            av[i] = (idx >= 0 && idx < W_) ? a_l[c * W_ + idx] : 0.f;
        }
        float wt[TAPS_];
        #pragma unroll
        for (int t = 0; t < TAPS_; ++t) wt[t] = ldg1(w2, fl, (size_t)o * C_ * TAPS_ + c * TAPS_ + t);
        #pragma unroll
        for (int w = 0; w < 48; ++w) {
            #pragma unroll
            for (int t = 0; t < TAPS_; ++t) acc[w] += av[w + t] * wt[t];
        }
    }

    float bv = ldg1(bias2, fl, o);
    size_t obase = ((size_t)(bb * C_ + o)) * HW_ + (size_t)h * W_ + w0;
    if (fl) {
        const float4* px4 = (const float4*)((const float*)x + obase);
        float4* po4 = (float4*)((float*)out + obase);
        #pragma unroll
        for (int v = 0; v < 12; ++v) {
            float4 xi = px4[v];
            float4 ro;
            ro.x = acc[v * 4 + 0] + bv + xi.x;
            ro.y = acc[v * 4 + 1] + bv + xi.y;
            ro.z = acc[v * 4 + 2] + bv + xi.z;
            ro.w = acc[v * 4 + 3] + bv + xi.w;
            po4[v] = ro;
        }
    } else {
        const uint4* px4 = (const uint4*)((const bf16*)x + obase);
        uint4* po4 = (uint4*)((bf16*)out + obase);
        #pragma unroll
        for (int v = 0; v < 6; ++v) {
            U8 xi; xi.u = px4[v];
            U8 ro;
            #pragma unroll
            for (int j = 0; j < 8; ++j)
                ro.h[j] = __float2bfloat16(acc[v * 8 + j] + bv + b2f(xi.h[j]));
            po4[v] = ro.u;
        }
    }
}

// ---------------------------------------------------------------------------
extern "C" void kernel_launch(void* const* d_in, const int* in_sizes, int n_in,
                              void* d_out, int out_size, void* d_ws, size_t ws_size,
                              hipStream_t stream) {
    const void* x    = d_in[0];
    const void* sw   = d_in[1];
    const void* sb   = d_in[2];
    const void* cw1  = d_in[3];
    const void* cb1  = d_in[4];
    const void* cw2  = d_in[5];
    const void* cb2  = d_in[6];
    const void* w2   = d_in[7];
    const void* b2   = d_in[8];

    int*   flag = (int*)d_ws;                       // 4 B
    float* g    = (float*)((char*)d_ws + 256);      // 256 f32
    float* cfn  = (float*)((char*)d_ws + 2048);     // 4*64*9 f32

    hipLaunchKernelGGL(k_detect, dim3(1), dim3(256), 0, stream, x, sw, flag);
    hipLaunchKernelGGL(k_mean, dim3(B_ * C_), dim3(256), 0, stream, x, flag, g);
    hipLaunchKernelGGL(k_cf, dim3(1), dim3(256), 0, stream, g, cw1, cb1, cw2, cb2, flag, cfn);
    hipLaunchKernelGGL(k_main, dim3(B_ * H_), dim3(256), 0, stream,
                       x, sw, sb, cfn, w2, b2, flag, (void*)d_out);
}